// Round 11
// baseline (129.094 us; speedup 1.0000x reference)
//
#include <hip/hip_runtime.h>
#include <hip/hip_bf16.h>

#define DIM  512
#define FEAT 64
#define BATCH 2048

#define D_PER_BLOCK 64     // 8 d-groups; dq = id&7 -> one d-group per XCD (W slice L2-hot)
#define NITER 16           // D_PER_BLOCK / 4 waves

using bf16x8 = __attribute__((ext_vector_type(8))) short;
using f32x4  = __attribute__((ext_vector_type(4))) float;

__device__ inline short f2bf(float f) {
    unsigned int u = __float_as_uint(f);
    u += 0x7fffu + ((u >> 16) & 1u);
    return (short)(u >> 16);
}

__device__ inline bf16x8 cvt8(float4 a, float4 b) {
    bf16x8 r;
    r[0] = f2bf(a.x); r[1] = f2bf(a.y); r[2] = f2bf(a.z); r[3] = f2bf(a.w);
    r[4] = f2bf(b.x); r[5] = f2bf(b.y); r[6] = f2bf(b.z); r[7] = f2bf(b.w);
    return r;
}

// ---- pre-pass (R6-verified): W f32 [512][64][64] -> bf16 MFMA-fragment layout ----
// ws[short] index = ((d*8 + g8)*64 + lane)*8, g8 = ks*4 + mt.
// Fragment lane l: A rows mt*16+(l&15), k = ks*32+(l>>4)*8 .. +7.
__global__ __launch_bounds__(256)
void w_prep(const float* __restrict__ W, short* __restrict__ ws) {
    const int d = blockIdx.x;
    const int t = threadIdx.x;
    const int l = t & 63, g0 = t >> 6;
#pragma unroll
    for (int h = 0; h < 2; ++h) {
        const int g8 = g0 + h * 4;
        const int mt = g8 & 3, ks = g8 >> 2;
        const float* src = W + ((size_t)d * FEAT + mt * 16 + (l & 15)) * FEAT
                             + ks * 32 + (l >> 4) * 8;
        float4 w0 = *(const float4*)src;
        float4 w1 = *(const float4*)(src + 4);
        *(bf16x8*)(ws + ((size_t)(d * 8 + g8) * 64 + l) * 8) = cvt8(w0, w1);
    }
}

// ---- main: block owns (16 rows x 64 consecutive d); waves take 4 adjacent d per
// iteration and advance -> all 16 row-streams consumed contiguously (reads+writes). ----
template<bool PRE>
__global__ __launch_bounds__(256, 2)   // VGPR cap 128; need ~108 (R3/R8 lesson: never cap below need)
void split_linear_main(const float* __restrict__ x,
                       const float* __restrict__ W,
                       const short* __restrict__ Wb,
                       const float* __restrict__ bias,
                       float* __restrict__ out)
{
    __shared__ float obuf[4][1024];   // wave-private transpose buffer (R7/R9 scheme)

    const int id = blockIdx.x;        // 0..1023
    const int dq = id & 7;            // d-group == XCD (id%8 round-robin)
    const int rt = id >> 3;           // row-tile 0..127
    const int d0 = dq * D_PER_BLOCK;
    const int b0 = rt * 16;

    const int tid  = threadIdx.x;
    const int wave = tid >> 6;
    const int lane = tid & 63;
    const int lr   = lane & 15;       // B-col (batch row) / A-row-within-16 / store chunk
    const int lk   = lane >> 4;       // k-group / store row-quad

    const int dw = d0 + wave;         // wave's base d; advances by 4 per iteration

    const float* xp  = x    + ((size_t)(b0 + lr) * DIM + dw) * FEAT + lk * 8;
    const float* bp  = bias + (size_t)dw * FEAT + lr * 4;            // store-side: cc==lr
    const short* wbp = Wb   + (size_t)dw * 4096 + lane * 8;
    float*       opb = out  + ((size_t)b0 * DIM + dw) * FEAT + lr * 4;
    float* sl = &obuf[wave][0];

    float4 xc[4], xn[4];
    f32x4 bc, bn;

    auto LOADX = [&](float4* xr, int i) {
        const float* xq = xp + (size_t)i * 256;          // d += 4 -> +256 floats
        xr[0] = *(const float4*)(xq);
        xr[1] = *(const float4*)(xq + 4);
        xr[2] = *(const float4*)(xq + 32);
        xr[3] = *(const float4*)(xq + 36);
    };
    auto LOADB = [&](int i) -> f32x4 {
        return *(const f32x4*)(bp + (size_t)i * 256);
    };

    auto BODY = [&](float4* xr, f32x4 bv, int i) {
        // W fragments for this d (single-buffered; ws slice is L2-hot per XCD)
        bf16x8 wf[8];
        if (PRE) {
            const short* wq = wbp + (size_t)i * 16384;   // d += 4 -> +4*4096 shorts
#pragma unroll
            for (int g = 0; g < 8; ++g)
                wf[g] = *(const bf16x8*)(wq + g * 512);
        } else {
            const float* wq = W + ((size_t)(dw + i * 4) * FEAT) * FEAT;
#pragma unroll
            for (int g = 0; g < 8; ++g) {
                const int mt = g & 3, ks = g >> 2;
                const float* p = wq + ((size_t)(mt * 16 + lr)) * FEAT + ks * 32 + lk * 8;
                float4 a = *(const float4*)p;
                float4 b = *(const float4*)(p + 4);
                wf[g] = cvt8(a, b);
            }
        }

        bf16x8 af0 = cvt8(xr[0], xr[1]);   // ks = 0
        bf16x8 af1 = cvt8(xr[2], xr[3]);   // ks = 1

        f32x4 acc[4] = {{0.f,0.f,0.f,0.f},{0.f,0.f,0.f,0.f},
                        {0.f,0.f,0.f,0.f},{0.f,0.f,0.f,0.f}};
#pragma unroll
        for (int mt = 0; mt < 4; ++mt)
            acc[mt] = __builtin_amdgcn_mfma_f32_16x16x32_bf16(wf[mt],     af0, acc[mt], 0, 0, 0);
#pragma unroll
        for (int mt = 0; mt < 4; ++mt)
            acc[mt] = __builtin_amdgcn_mfma_f32_16x16x32_bf16(wf[4 + mt], af1, acc[mt], 0, 0, 0);

        // transpose into wave-private obuf (per-wave DS ops in-order; R8/R9-verified)
        // lane (lr,lk), mt holds out[row lr][g = mt*16+lk*4 ..+3] -> chunk c = mt*4+lk
#pragma unroll
        for (int mt = 0; mt < 4; ++mt) {
            const int c  = mt * 4 + lk;
            const int pc = c ^ (lr & 7);
            *(f32x4*)&sl[lr * 64 + pc * 4] = acc[mt];
        }

        // dense NT store-back + bias: instr j covers rows j*4..+3, 256B/row, d-sequential
#pragma unroll
        for (int j = 0; j < 4; ++j) {
            const int rr  = j * 4 + lk;
            const int pc2 = lr ^ (rr & 7);
            f32x4 v = *(const f32x4*)&sl[rr * 64 + pc2 * 4];
            v += bv;
            __builtin_nontemporal_store(v,
                (f32x4*)(opb + (size_t)rr * (DIM * FEAT) + (size_t)i * 256));
        }
    };

    LOADX(xc, 0); bc = LOADB(0);
    for (int i = 0; i < NITER; i += 2) {
        LOADX(xn, i + 1); bn = LOADB(i + 1);   // prefetch next-d x (HBM stream) + bias
        BODY(xc, bc, i);
        if (i + 2 < NITER) { LOADX(xc, i + 2); bc = LOADB(i + 2); }
        BODY(xn, bn, i + 1);
    }
}

extern "C" void kernel_launch(void* const* d_in, const int* in_sizes, int n_in,
                              void* d_out, int out_size, void* d_ws, size_t ws_size,
                              hipStream_t stream) {
    const float* x    = (const float*)d_in[0];
    const float* W    = (const float*)d_in[1];
    const float* bias = (const float*)d_in[2];
    float* out        = (float*)d_out;

    const size_t WSNEED = (size_t)DIM * 8 * 64 * 8 * sizeof(short);  // 4 MB
    dim3 block(256, 1, 1);
    dim3 grid((BATCH / 16) * (DIM / D_PER_BLOCK), 1, 1);             // 128*8 = 1024

    if (ws_size >= WSNEED) {
        short* ws = (short*)d_ws;
        w_prep<<<dim3(DIM), block, 0, stream>>>(W, ws);
        split_linear_main<true><<<grid, block, 0, stream>>>(x, nullptr, ws, bias, out);
    } else {
        split_linear_main<false><<<grid, block, 0, stream>>>(x, W, nullptr, bias, out);
    }
}

// Round 12
// 120.598 us; speedup vs baseline: 1.0704x; 1.0704x over previous
//
#include <hip/hip_runtime.h>
#include <hip/hip_bf16.h>

#define DIM  512
#define FEAT 64
#define BATCH 2048

#define DPB    64    // consecutive d per block
#define NTILES 16    // DPB / 4

using bf16x8 = __attribute__((ext_vector_type(8))) short;
using f32x4  = __attribute__((ext_vector_type(4))) float;

typedef __attribute__((address_space(3))) float lds_f;
typedef __attribute__((address_space(1))) const float glb_f;

__device__ inline short f2bf(float f) {
    unsigned int u = __float_as_uint(f);
    u += 0x7fffu + ((u >> 16) & 1u);
    return (short)(u >> 16);
}

__device__ inline bf16x8 cvt8(float4 a, float4 b) {
    bf16x8 r;
    r[0] = f2bf(a.x); r[1] = f2bf(a.y); r[2] = f2bf(a.z); r[3] = f2bf(a.w);
    r[4] = f2bf(b.x); r[5] = f2bf(b.y); r[6] = f2bf(b.z); r[7] = f2bf(b.w);
    return r;
}

// ---- pre-pass (R6/R11-verified): W f32 -> bf16 MFMA-fragment layout in ws ----
// ws[short] idx = ((d*8 + g8)*64 + lane)*8, g8 = ks*4 + mt.
__global__ __launch_bounds__(256)
void w_prep(const float* __restrict__ W, short* __restrict__ ws) {
    const int d = blockIdx.x;
    const int t = threadIdx.x;
    const int l = t & 63, g0 = t >> 6;
#pragma unroll
    for (int h = 0; h < 2; ++h) {
        const int g8 = g0 + h * 4;
        const int mt = g8 & 3, ks = g8 >> 2;
        const float* src = W + ((size_t)d * FEAT + mt * 16 + (l & 15)) * FEAT
                             + ks * 32 + (l >> 4) * 8;
        *(bf16x8*)(ws + ((size_t)(d * 8 + g8) * 64 + l) * 8)
            = cvt8(*(const float4*)src, *(const float4*)(src + 4));
    }
}

// ---- main: block = 16 rows x 64 consecutive d. Per tile (4 d): each stage/store
// instruction covers 1 row x 1KB contiguous; tiles advance +1KB per row ->
// 16KB sequential HBM runs on BOTH read and write sides. ----
template<bool PRE>
__global__ __launch_bounds__(256, 2)   // VGPR cap 128; need ~110 (never cap below need)
void split_linear_main(const float* __restrict__ x,
                       const float* __restrict__ W,
                       const short* __restrict__ Wb,
                       const float* __restrict__ bias,
                       float* __restrict__ out)
{
    // shared super-tile: [slot][16 rows][4 dsub * 64 f] = 2 x 16KB.
    // 16B-chunk XOR(row&7) swizzle within each [row][dsub] 256B region (R8/R9 scheme).
    __shared__ float slot[2][16][256];

    const int id = blockIdx.x;        // 0..1023
    const int dc = id & 7;            // d-chunk -> XCD-affine (W slice 512KB, L2-hot)
    const int rc = id >> 3;           // row-chunk 0..127
    const int d0 = dc * DPB;
    const int b0 = rc * 16;

    const int tid  = threadIdx.x;
    const int wave = tid >> 6;
    const int lane = tid & 63;
    const int lr   = lane & 15;       // B-col (batch row) / A-row-within-16
    const int lk   = lane >> 4;       // k-group

    // wave w stages+stores rows 4w..4w+3; computes d-slice (dsub = w).
    auto stage = [&](int s, int t) {
#pragma unroll
        for (int i = 0; i < 4; ++i) {
            const int r = wave * 4 + i;
            const float* gp = x + ((size_t)(b0 + r) * DIM + d0 + t * 4) * FEAT
                                + (lane >> 4) * 64 + (((lane & 15) ^ (r & 7)) << 2);
            __builtin_amdgcn_global_load_lds((glb_f*)gp, (lds_f*)&slot[s][r][0], 16, 0, 0);
        }
    };

    // per-wave d at tile t: d = d0 + t*4 + wave
    const short* wbp = Wb + ((size_t)(d0 + wave)) * 4096 + lane * 8;
    const float* bsp = bias + (size_t)d0 * FEAT + lane * 4;   // store-side bias: 1 f32x4/lane

    auto LOADW = [&](bf16x8 (&wf)[8], f32x4& bv, int t) {
        if (PRE) {
            const short* wq = wbp + (size_t)t * 4 * 4096;
#pragma unroll
            for (int g = 0; g < 8; ++g)
                wf[g] = *(const bf16x8*)(wq + g * 512);
        } else {
            const float* wq = W + (size_t)(d0 + t * 4 + wave) * FEAT * FEAT;
#pragma unroll
            for (int g = 0; g < 8; ++g) {
                const int mt = g & 3, ks = g >> 2;
                const float* p = wq + (size_t)(mt * 16 + lr) * FEAT + ks * 32 + lk * 8;
                wf[g] = cvt8(*(const float4*)p, *(const float4*)(p + 4));
            }
        }
        bv = *(const f32x4*)(bsp + t * 256);
    };

    auto BODY = [&](bf16x8 (&wfc)[8], bf16x8 (&wfn)[8], f32x4& bvc, f32x4& bvn, int t) {
        const int s = t & 1;
        // per-wave counted vmcnt (issue order pinned by sched_barriers):
        // steady outstanding: stage(t)4, W(t)~9, stores(t-1)4, stage(t+1)4;
        // need stage(t)+W(t) -> keep newest 8. Edges: t=0 / t=15 -> keep 4.
        if (t == 0 || t == NTILES - 1)
            asm volatile("s_waitcnt vmcnt(4)" ::: "memory");
        else
            asm volatile("s_waitcnt vmcnt(8)" ::: "memory");
        __builtin_amdgcn_s_barrier();               // #1 tile t fully staged
        __builtin_amdgcn_sched_barrier(0);

        if (t + 1 < NTILES) LOADW(wfn, bvn, t + 1); // prefetch next W+bias (keeps counting)

        const float* sl = &slot[s][0][0];
        const int rbase = lr * 256 + wave * 64;
        float4 p0a = *(const float4*)&sl[rbase + (((lk * 2 + 0) ^ (lr & 7)) << 2)];
        float4 p0b = *(const float4*)&sl[rbase + (((lk * 2 + 1) ^ (lr & 7)) << 2)];
        float4 p1a = *(const float4*)&sl[rbase + (((8 + lk * 2 + 0) ^ (lr & 7)) << 2)];
        float4 p1b = *(const float4*)&sl[rbase + (((8 + lk * 2 + 1) ^ (lr & 7)) << 2)];

        bf16x8 af0 = cvt8(p0a, p0b);   // ks = 0
        bf16x8 af1 = cvt8(p1a, p1b);   // ks = 1

        f32x4 acc[4] = {{0.f,0.f,0.f,0.f},{0.f,0.f,0.f,0.f},
                        {0.f,0.f,0.f,0.f},{0.f,0.f,0.f,0.f}};
#pragma unroll
        for (int mt = 0; mt < 4; ++mt)
            acc[mt] = __builtin_amdgcn_mfma_f32_16x16x32_bf16(wfc[mt],     af0, acc[mt], 0, 0, 0);
#pragma unroll
        for (int mt = 0; mt < 4; ++mt)
            acc[mt] = __builtin_amdgcn_mfma_f32_16x16x32_bf16(wfc[4 + mt], af1, acc[mt], 0, 0, 0);

        asm volatile("s_waitcnt lgkmcnt(0)" ::: "memory");
        __builtin_amdgcn_s_barrier();               // #2 all waves done reading slot
        __builtin_amdgcn_sched_barrier(0);

        // transpose into the consumed slot: lane(lr,lk), mt -> [lr][wave][c=mt*4+lk]
        float* slw = &slot[s][0][0];
#pragma unroll
        for (int mt = 0; mt < 4; ++mt) {
            const int pc = (mt * 4 + lk) ^ (lr & 7);
            *(f32x4*)&slw[lr * 256 + wave * 64 + pc * 4] = acc[mt];
        }
        asm volatile("s_waitcnt lgkmcnt(0)" ::: "memory");
        __builtin_amdgcn_s_barrier();               // #3 transposed data visible
        __builtin_amdgcn_sched_barrier(0);

        // dense NT store: instr j = row 4w+j, 1KB contiguous; +1KB per tile (sequential)
#pragma unroll
        for (int j = 0; j < 4; ++j) {
            const int r = wave * 4 + j;
            f32x4 v = *(const f32x4*)&slw[r * 256 + (lane >> 4) * 64
                                          + (((lane & 15) ^ (r & 7)) << 2)];
            v += bvc;   // bias[d = d0+t*4+(lane>>4)][g = (lane&15)*4..+3]
            __builtin_nontemporal_store(v,
                (f32x4*)(out + ((size_t)(b0 + r) * DIM + d0 + t * 4) * FEAT + lane * 4));
        }
        __builtin_amdgcn_sched_barrier(0);
        if (t + 2 < NTILES) stage(s, t + 2);        // own rows only: no cross-wave hazard
        __builtin_amdgcn_sched_barrier(0);
    };

    bf16x8 wfA[8], wfB[8];
    f32x4 bvA, bvB;

    // prologue, order pinned for vmcnt accounting: stage(0), W(0), stage(1)
    stage(0, 0);
    __builtin_amdgcn_sched_barrier(0);
    LOADW(wfA, bvA, 0);
    __builtin_amdgcn_sched_barrier(0);
    stage(1, 1);
    __builtin_amdgcn_sched_barrier(0);

#pragma unroll
    for (int t = 0; t < NTILES; t += 2) {
        BODY(wfA, wfB, bvA, bvB, t);
        BODY(wfB, wfA, bvB, bvA, t + 1);
    }
}

extern "C" void kernel_launch(void* const* d_in, const int* in_sizes, int n_in,
                              void* d_out, int out_size, void* d_ws, size_t ws_size,
                              hipStream_t stream) {
    const float* x    = (const float*)d_in[0];
    const float* W    = (const float*)d_in[1];
    const float* bias = (const float*)d_in[2];
    float* out        = (float*)d_out;

    const size_t WSNEED = (size_t)DIM * 8 * 64 * 8 * sizeof(short);  // 4 MB
    dim3 block(256, 1, 1);
    dim3 grid((BATCH / 16) * (DIM / DPB), 1, 1);                     // 128*8 = 1024

    if (ws_size >= WSNEED) {
        short* ws = (short*)d_ws;
        w_prep<<<dim3(DIM), block, 0, stream>>>(W, ws);
        split_linear_main<true><<<grid, block, 0, stream>>>(x, nullptr, ws, bias, out);
    } else {
        split_linear_main<false><<<grid, block, 0, stream>>>(x, W, nullptr, bias, out);
    }
}